// Round 15
// baseline (90.354 us; speedup 1.0000x reference)
//
#include <hip/hip_runtime.h>

#define NR 4096      // rows per batch
#define DD 512       // feature dim
#define TWO_N 8192
#define MT2 32       // 8192/256 tiles per dim
#define NT2 528      // MT2*(MT2+1)/2
#define CH2 66       // NT2/8 per XCD

using bf16x8 = __attribute__((ext_vector_type(8))) short;   // 8 bf16 in 4 VGPRs
using f32x4  = __attribute__((ext_vector_type(4))) float;

__device__ __forceinline__ unsigned short f2bf(float f) {
    union { float f; unsigned u; } v; v.f = f;
    unsigned r = v.u + 0x7fff + ((v.u >> 16) & 1);   // round-to-nearest-even
    return (unsigned short)(r >> 16);
}

// Kernel 1: L2-normalize rows of A and B -> bf16 X = [nA; nB], fp32 d12[i] = nA_i . nB_i.
// Also zeroes S[8192] (2 elements per block).
__global__ __launch_bounds__(256) void ntx_nrm_kernel(const float* __restrict__ A,
                                                      const float* __restrict__ B,
                                                      unsigned short* __restrict__ X,
                                                      float* __restrict__ d12,
                                                      float* __restrict__ S) {
    const int row = blockIdx.x;
    const int t = threadIdx.x;            // 256 threads, 2 elems each
    const int lane = t & 63, wid = t >> 6;

    if (t < 2) S[row * 2 + t] = 0.f;

    const float2 av = *(const float2*)(A + row * DD + 2 * t);
    const float2 bv = *(const float2*)(B + row * DD + 2 * t);
    float sa = av.x * av.x + av.y * av.y;
    float sb = bv.x * bv.x + bv.y * bv.y;
#pragma unroll
    for (int o = 32; o; o >>= 1) { sa += __shfl_down(sa, o); sb += __shfl_down(sb, o); }

    __shared__ float red[12];
    if (lane == 0) { red[wid] = sa; red[4 + wid] = sb; }
    __syncthreads();
    const float ta = red[0] + red[1] + red[2] + red[3];
    const float tb = red[4] + red[5] + red[6] + red[7];
    const float ra = 1.f / fmaxf(sqrtf(ta), 1e-8f);
    const float rb = 1.f / fmaxf(sqrtf(tb), 1e-8f);
    const float nax = av.x * ra, nay = av.y * ra;
    const float nbx = bv.x * rb, nby = bv.y * rb;

    *(unsigned*)(X + row * DD + 2 * t) =
        (unsigned)f2bf(nax) | ((unsigned)f2bf(nay) << 16);
    *(unsigned*)(X + (NR + row) * DD + 2 * t) =
        (unsigned)f2bf(nbx) | ((unsigned)f2bf(nby) << 16);

    float dt = nax * nbx + nay * nby;
#pragma unroll
    for (int o = 32; o; o >>= 1) dt += __shfl_down(dt, o);
    if (lane == 0) red[8 + wid] = dt;
    __syncthreads();
    if (t == 0) d12[row] = red[8] + red[9] + red[10] + red[11];
}

// Kernel 2: logits[r,c] = 2 * X_r . Z_c, Z_c = X_{c^4096}.
// Round-15 (= R14 fixed): phase-split 256x256 / 8-wave structure with TRUE counted
// vmcnt: BK=32, THREE buffers per op (3 x 2 x 16 KB = 96 KB, fits LDS), prefetch
// distance 2 tiles. Per 16 K-tiles: 2 phases {ds_read half | stage t+2 chunk ->
// barrier -> lgkm(0)+sched_barrier -> setprio MFMA -> barrier}; ONE vmcnt(4) per
// tile at close (retires exactly t+1's 4 loads, keeps t+2's in flight - drains
// only at the t=14 tail). R10-verified BK=32 swizzle: phys_slot = slot^((row>>1)&3),
// inverse on global source (0 conflicts). Triangle u<=v, 4x4 supertiles + XCD remap.
__global__ __launch_bounds__(512, 1) void ntx_gemm_lse_kernel(const unsigned short* __restrict__ X,
                                                              float* __restrict__ S) {
    // ---- bid -> XCD-contiguous supertile-ordered sid -> (u,v) ----
    const int bid = blockIdx.x;
    const int sid = (bid & 7) * CH2 + (bid >> 3);
    int u, v;
    if (sid < 448) {                     // off-diagonal supertile (U<V): 28 x 16
        const int s = sid >> 4, loc = sid & 15;
        int U = 0;
        while (7 * (U + 1) - (U + 1) * U / 2 <= s) ++U;      // offExcl(U+1) <= s
        const int V = U + 1 + (s - (7 * U - U * (U - 1) / 2));
        u = U * 4 + (loc >> 2);
        v = V * 4 + (loc & 3);
    } else {                             // diagonal supertile (U==V): 8 x 10, lu<=lv
        const int s2 = sid - 448;
        const int U = s2 / 10, loc = s2 % 10;
        int lu = 0;
        while ((lu + 1) * 4 - (lu + 1) * lu / 2 <= loc) ++lu; // offIncl(lu+1) <= loc
        const int lv = lu + (loc - (lu * 4 - lu * (lu - 1) / 2));
        u = U * 4 + lu;
        v = U * 4 + lv;
    }
    const bool fixedTile = (u == v);
    const int rowTile = u * 256, colTile = (v ^ 16) * 256;

    __shared__ unsigned short As[3][256 * 32];   // 3 x 16 KB
    __shared__ unsigned short Bs[3][256 * 32];   // 3 x 16 KB  (96 KB total)

    const int t = threadIdx.x;            // 0..511
    const int lane = t & 63, wid = t >> 6;         // 8 waves
    const int waveM = wid >> 2, waveN = wid & 3;   // 2 x 4
    const int lr = lane & 15, grp = lane >> 4;
    const int swr = (lr >> 1) & 3;        // read-side swizzle key ((row>>1)&3)
    const int kslot = (grp ^ swr) * 8;    // physical 16B slot (ushorts)

    f32x4 acc[8][4] = {};
    bf16x8 af[4];                         // A-frags of current mh
    bf16x8 bf[4];                         // B-frags (all 4 n, reused across both phases)

    // staging: per buffer per op = 256 rows x 64B = 16 chunks of 1KB (16 rows).
    // chunk ci = wid*2 + q; lane l -> row = ci*16 + l/4, phys slot = l&3,
    // LDS ushort idx = ci*512 + l*8. Inverse source swizzle: phys p at row r holds
    // logical p^((r>>1)&3); (r>>1)&3 = (l>>3)&3 -> source col = kt+((l&3)^((l>>3)&3))*8.
    const int srow = lane >> 2;                              // 0..15 within chunk
    const int scol = ((lane & 3) ^ ((lane >> 3) & 3)) * 8;   // swizzled source col

    auto STAGE1 = [&](int sel, int kt, int q) {   // one A chunk + one B chunk (2 loads)
        const int ci = wid * 2 + q;
        const int r  = ci * 16 + srow;
        const int lo = ci * 512 + lane * 8;
        __builtin_amdgcn_global_load_lds(
            (const __attribute__((address_space(1))) unsigned*)(X + (size_t)(rowTile + r) * DD + kt + scol),
            (__attribute__((address_space(3))) unsigned*)&As[sel][lo], 16, 0, 0);
        __builtin_amdgcn_global_load_lds(
            (const __attribute__((address_space(1))) unsigned*)(X + (size_t)((colTile + r) ^ NR) * DD + kt + scol),
            (__attribute__((address_space(3))) unsigned*)&Bs[sel][lo], 16, 0, 0);
    };

    auto LDA = [&](int sel, int mh) {     // 4 ds_read_b128
#pragma unroll
        for (int mm = 0; mm < 4; ++mm)
            af[mm] = *(const bf16x8*)&As[sel][(waveM * 128 + (mh * 4 + mm) * 16 + lr) * 32 + kslot];
    };
    auto LDB = [&](int sel) {             // 4 ds_read_b128
#pragma unroll
        for (int n = 0; n < 4; ++n)
            bf[n] = *(const bf16x8*)&Bs[sel][(waveN * 64 + n * 16 + lr) * 32 + kslot];
    };
    auto QUAD = [&](int mh) {             // 16 MFMA (4m x 4n)
        __builtin_amdgcn_s_setprio(1);
#pragma unroll
        for (int mm = 0; mm < 4; ++mm)
#pragma unroll
            for (int n = 0; n < 4; ++n)
                acc[mh * 4 + mm][n] = __builtin_amdgcn_mfma_f32_16x16x32_bf16(
                    af[mm], bf[n], acc[mh * 4 + mm][n], 0, 0, 0);
        __builtin_amdgcn_s_setprio(0);
    };

    // ---- prologue: stage tiles 0,1 (8 loads/thread); retire tile 0's 4 only ----
    STAGE1(0, 0, 0);  STAGE1(0, 0, 1);
    STAGE1(1, 32, 0); STAGE1(1, 32, 1);
    asm volatile("s_waitcnt vmcnt(4)" ::: "memory");   // tile 0 landed; tile 1 in flight
    __builtin_amdgcn_s_barrier();

    for (int tt = 0; tt < 16; ++tt) {
        const int sel = tt % 3;
        const int nxt = (tt + 2) % 3;
        const int kn = (tt + 2) * 32;
        const bool st = (tt < 14);
        // ---- phase 0: mh=0 half ----
        LDB(sel); LDA(sel, 0);                                  // 8 ds_reads
        if (st) STAGE1(nxt, kn, 0);
        __builtin_amdgcn_s_barrier();
        asm volatile("s_waitcnt lgkmcnt(0)" ::: "memory");
        __builtin_amdgcn_sched_barrier(0);                      // rule #18
        QUAD(0);
        __builtin_amdgcn_s_barrier();
        // ---- phase 1: mh=1 half (B-frags reused) ----
        LDA(sel, 1);                                            // 4 ds_reads
        if (st) STAGE1(nxt, kn, 1);
        __builtin_amdgcn_s_barrier();
        asm volatile("s_waitcnt lgkmcnt(0)" ::: "memory");
        __builtin_amdgcn_sched_barrier(0);
        QUAD(1);
        // counted wait for next tile's buffer (never drains mid-loop):
        if (tt < 14)       asm volatile("s_waitcnt vmcnt(4)" ::: "memory");  // retire t+1's 4, keep t+2's 4
        else if (tt == 14) asm volatile("s_waitcnt vmcnt(0)" ::: "memory");  // tail: tile 15
        __builtin_amdgcn_s_barrier();
    }

    // ---- Epilogue ----
    // C/D layout: col = lane&15 (lr), row = grp*4 + reg.
#pragma unroll
    for (int m = 0; m < 8; ++m)
#pragma unroll
        for (int n = 0; n < 4; ++n)
#pragma unroll
            for (int reg = 0; reg < 4; ++reg) {
                const int R = rowTile + waveM * 128 + m * 16 + grp * 4 + reg;
                const int C = colTile + waveN * 64 + n * 16 + lr;
                const bool masked = fixedTile && (C == (R ^ NR));
                acc[m][n][reg] = masked ? 0.f : __expf(acc[m][n][reg] * 2.0f);
            }

    // row sums -> S[R]
#pragma unroll
    for (int m = 0; m < 8; ++m)
#pragma unroll
        for (int reg = 0; reg < 4; ++reg) {
            float rs = acc[m][0][reg] + acc[m][1][reg] + acc[m][2][reg] + acc[m][3][reg];
            rs += __shfl_xor(rs, 1);
            rs += __shfl_xor(rs, 2);
            rs += __shfl_xor(rs, 4);
            rs += __shfl_xor(rs, 8);
            if (lr == 0) {
                const int R = rowTile + waveM * 128 + m * 16 + grp * 4 + reg;
                atomicAdd(&S[R], rs);
            }
        }

    // mirror col sums -> S[C^N]  (skip on fixed tiles: they'd double-count)
    if (!fixedTile) {
#pragma unroll
        for (int n = 0; n < 4; ++n) {
            float cs = 0.f;
#pragma unroll
            for (int m = 0; m < 8; ++m)
#pragma unroll
                for (int reg = 0; reg < 4; ++reg)
                    cs += acc[m][n][reg];
            cs += __shfl_xor(cs, 16);
            cs += __shfl_xor(cs, 32);
            if (grp == 0) {
                const int C = colTile + waveN * 64 + n * 16 + lr;
                atomicAdd(&S[C ^ NR], cs);
            }
        }
    }
}

// Kernel 3: loss partials: 32 blocks x 256 thr, one r each; block-reduce then
// atomicAdd(out, partial/2N). d_out is zeroed via hipMemsetAsync each call.
__global__ __launch_bounds__(256) void ntx_loss_kernel(const float* __restrict__ S,
                                                       const float* __restrict__ d12,
                                                       float* __restrict__ out) {
    const int t = threadIdx.x;
    const int r = blockIdx.x * 256 + t;
    float a = __logf(S[r]) - 2.0f * d12[r & (NR - 1)];
    const int lane = t & 63, wid = t >> 6;
#pragma unroll
    for (int o = 32; o; o >>= 1) a += __shfl_down(a, o);
    __shared__ float red[4];
    if (lane == 0) red[wid] = a;
    __syncthreads();
    if (t == 0) atomicAdd(out, (red[0] + red[1] + red[2] + red[3]) * (1.f / (float)TWO_N));
}

extern "C" void kernel_launch(void* const* d_in, const int* in_sizes, int n_in,
                              void* d_out, int out_size, void* d_ws, size_t ws_size,
                              hipStream_t stream) {
    const float* A = (const float*)d_in[0];
    const float* B = (const float*)d_in[1];

    // workspace layout
    unsigned short* X = (unsigned short*)d_ws;                    // 8192*512*2 = 8 MB
    float* S   = (float*)((char*)d_ws + (size_t)TWO_N * DD * 2);  // 32 KB
    float* d12 = (float*)((char*)S + (size_t)TWO_N * 4);          // 16 KB

    (void)hipMemsetAsync(d_out, 0, sizeof(float), stream);        // loss accumulator

    ntx_nrm_kernel<<<NR, 256, 0, stream>>>(A, B, X, d12, S);

    ntx_gemm_lse_kernel<<<NT2, 512, 0, stream>>>(X, S);

    ntx_loss_kernel<<<TWO_N / 256, 256, 0, stream>>>(S, d12, (float*)d_out);
}